// Round 2
// baseline (1965534.766 us; speedup 1.0000x reference)
//
#include <hip/hip_runtime.h>

#define S_LEN 1024
#define BATCH 64
#define I_DIM 256
#define H_DIM 512
#define NCL 8      // clusters (8 batch rows each) — one per XCD in fast path
#define NRK 8      // WGs per cluster (64 feats each)
#define ROWS 8
#define FPW 64     // feats per WG (16 per wave, full K per wave)
#define HSTR 520   // LDS row stride (bf16 elems) for h: 16B-aligned rows
#define XSTR 264   // LDS row stride (bf16) for x staging in precompute
#define POLL_CAP 16384
#define HSHAKE_CAP 200000

typedef short short8 __attribute__((ext_vector_type(8)));
typedef float floatx4 __attribute__((ext_vector_type(4)));
typedef unsigned short ushortx4 __attribute__((ext_vector_type(4)));

__device__ inline unsigned short f2bf(float x){
  unsigned u = __float_as_uint(x);
  u += 0x7fffu + ((u >> 16) & 1u);           // RNE
  return (unsigned short)(u >> 16);
}
__device__ inline float bf2f(unsigned short s){
  return __uint_as_float(((unsigned)s) << 16);
}
__device__ inline float fast_tanh(float x){
  float e = __expf(2.0f * x);                // inf-safe: +inf -> 1, 0 -> -1
  return 1.0f - 2.0f / (e + 1.0f);
}
__device__ inline float fast_sigmoid(float x){
  return 1.0f / (1.0f + __expf(-x));
}
__device__ inline short8 cvt8(const float* p){
  short8 r;
#pragma unroll
  for (int j = 0; j < 8; j++) r[j] = (short)f2bf(p[j]);
  return r;
}

// ---- scoped comm helpers: fast = XCD-local via L2 (sc0), slow = device via L3 (sc1)
__device__ inline void st_u32(void* p, unsigned v, bool fast){
  if (fast) asm volatile("global_store_dword %0, %1, off sc0" :: "v"(p), "v"(v) : "memory");
  else      asm volatile("global_store_dword %0, %1, off sc1" :: "v"(p), "v"(v) : "memory");
}
__device__ inline void st_f128(void* p, floatx4 v, bool fast){
  if (fast) asm volatile("global_store_dwordx4 %0, %1, off sc0" :: "v"(p), "v"(v) : "memory");
  else      asm volatile("global_store_dwordx4 %0, %1, off sc1" :: "v"(p), "v"(v) : "memory");
}
__device__ inline unsigned ld_flag(const void* p, bool fast){
  unsigned v;
  if (fast) asm volatile("global_load_dword %0, %1, off sc0\n\ts_waitcnt vmcnt(0)"
                         : "=&v"(v) : "v"(p) : "memory");
  else      asm volatile("global_load_dword %0, %1, off sc1\n\ts_waitcnt vmcnt(0)"
                         : "=&v"(v) : "v"(p) : "memory");
  return v;
}

// ---------------------------------------------------------------------------
// Kernel W: pre-convert W_in and tau_w1[:, :256] to bf16. (unchanged)
// ---------------------------------------------------------------------------
__global__ __launch_bounds__(256) void convert_weights_kernel(
  const float* __restrict__ W_in, const float* __restrict__ tau_w1,
  unsigned short* __restrict__ Wbf, unsigned short* __restrict__ Tbf)
{
  const int f = blockIdx.x, k = threadIdx.x;
  Wbf[f * I_DIM + k] = f2bf(W_in[(size_t)f * I_DIM + k]);
  Tbf[f * I_DIM + k] = f2bf(tau_w1[(size_t)f * (I_DIM + H_DIM) + k]);
}

// ---------------------------------------------------------------------------
// Kernel P: A_in[t][F][b], A_tau[t][F][b]  (unchanged)
// ---------------------------------------------------------------------------
__global__ __launch_bounds__(256) void precompute_kernel(
  const float* __restrict__ x, const unsigned short* __restrict__ Wbf,
  const unsigned short* __restrict__ Tbf,
  const float* __restrict__ b_in, const float* __restrict__ tau_b1,
  unsigned short* __restrict__ A_in, unsigned short* __restrict__ A_tau)
{
  __shared__ unsigned short xs[BATCH * XSTR];
  const int t = blockIdx.x, tid = threadIdx.x;
  {
    const int br = tid >> 2, pp = tid & 3;
    const float* xrow = x + ((size_t)br * S_LEN + t) * I_DIM + pp * 64;
    unsigned short* drow = xs + br * XSTR + pp * 64;
#pragma unroll
    for (int c = 0; c < 16; c++){
      float4 v = *(const float4*)(xrow + c * 4);
      ushortx4 o; o[0] = f2bf(v.x); o[1] = f2bf(v.y); o[2] = f2bf(v.z); o[3] = f2bf(v.w);
      *(ushortx4*)(drow + c * 4) = o;
    }
  }
  __syncthreads();

  const int w = tid >> 6, l15 = tid & 15, q = (tid & 63) >> 4;
#pragma unroll 1
  for (int fb = 0; fb < 8; fb++){
    const int F = fb * 64 + w * 16 + l15;
    floatx4 accf[4], acct[4];
#pragma unroll
    for (int m = 0; m < 4; m++){ accf[m] = (floatx4){0,0,0,0}; acct[m] = (floatx4){0,0,0,0}; }
#pragma unroll
    for (int kc = 0; kc < 8; kc++){
      const int k0 = kc * 32 + q * 8;
      short8 bw = *(const short8*)&Wbf[F * I_DIM + k0];
      short8 bt = *(const short8*)&Tbf[F * I_DIM + k0];
#pragma unroll
      for (int m = 0; m < 4; m++){
        short8 a = *(const short8*)&xs[(m * 16 + l15) * XSTR + k0];
        accf[m] = __builtin_amdgcn_mfma_f32_16x16x32_bf16(a, bw, accf[m], 0, 0, 0);
        acct[m] = __builtin_amdgcn_mfma_f32_16x16x32_bf16(a, bt, acct[m], 0, 0, 0);
      }
    }
    const float bi = b_in[F], bt1 = tau_b1[F];
#pragma unroll
    for (int m = 0; m < 4; m++){
      ushortx4 pf, pt;
#pragma unroll
      for (int i2 = 0; i2 < 4; i2++){ pf[i2] = f2bf(accf[m][i2] + bi); pt[i2] = f2bf(acct[m][i2] + bt1); }
      const size_t base = ((size_t)t * H_DIM + F) * BATCH + m * 16 + q * 4;
      *(ushortx4*)(A_in + base) = pf;
      *(ushortx4*)(A_tau + base) = pt;
    }
  }
}

// ---------------------------------------------------------------------------
// Kernel S: persistent scan, XCD-local clusters.
//   8 clusters x 8 batch rows; 8 ranks x 64 feats; 64 WGs, 1 per CU.
//   Runtime handshake (CAPPED spin) discovers WG->XCD placement; if each XCD
//   holds exactly 8 WGs, cluster := XCC_ID and all comm runs sc0 (XCD L2).
//   Else deterministic sc1 fallback (round-0 semantics). POLL_CAP bounds the
//   per-step flag wait so no protocol bug can hang the GPU.
// ---------------------------------------------------------------------------
__global__ __launch_bounds__(256, 1) void scan_kernel(
  const float* __restrict__ h0, const float* __restrict__ W_rec,
  const float* __restrict__ tau_w1, const float* __restrict__ tau_w2,
  const float* __restrict__ tau_b2_p, const float* __restrict__ gamma,
  const float* __restrict__ beta,
  const unsigned short* __restrict__ A_in, const unsigned short* __restrict__ A_tau,
  unsigned short* __restrict__ bc_f, float* __restrict__ bc_td,
  unsigned int* __restrict__ flags,
  float* __restrict__ out0, float* __restrict__ outh, float* __restrict__ outtau)
{
  __shared__ unsigned short hB[16 * HSTR];   // rows 8..15 stay zero (MFMA M=16 pad)
  __shared__ int sh_cl, sh_rk, sh_fast;

  const int tid = threadIdx.x;

  // ---- one-time handshake: discover XCD, assign cluster/rank, pick scope ----
  if (tid == 0){
    unsigned xcd;
    asm volatile("s_getreg_b32 %0, hwreg(HW_REG_XCC_ID)" : "=s"(xcd));
    xcd &= 7u;
    unsigned* initcnt = flags + 64;   // 8 entries
    unsigned* g_cnt   = flags + 80;   // 1 entry   (all zeroed by host memset)
    int slot = atomicAdd((int*)&initcnt[xcd], 1);
    __builtin_amdgcn_s_waitcnt(0);    // initcnt RMW at L3 before g_cnt RMW
    atomicAdd((int*)g_cnt, 1);
    unsigned seen = 0; int hcap = 0;
    for (;;){
      seen = __hip_atomic_load(g_cnt, __ATOMIC_RELAXED, __HIP_MEMORY_SCOPE_AGENT);
      if (seen >= 64u || ++hcap > HSHAKE_CAP) break;   // capped: never hang
      __builtin_amdgcn_s_sleep(8);
    }
    int ok = (seen >= 64u) ? 1 : 0;
#pragma unroll
    for (int x2 = 0; x2 < 8; x2++)
      ok &= (__hip_atomic_load(&initcnt[x2], __ATOMIC_RELAXED, __HIP_MEMORY_SCOPE_AGENT) == 8u);
    if (ok){ sh_cl = (int)xcd; sh_rk = slot; sh_fast = 1; }
    else   { sh_cl = (int)(blockIdx.x & 7); sh_rk = (int)(blockIdx.x >> 3); sh_fast = 0; }
  }
  for (int idx = tid; idx < 16 * HSTR; idx += 256) hB[idx] = 0;
  __syncthreads();
  const int cl = sh_cl, rank = sh_rk;
  const bool fast = (sh_fast != 0);

  const int w = tid >> 6, l64 = tid & 63, l15 = tid & 15, q = (tid & 63) >> 4;
  const int fl = l15;
  const int rb0 = (l64 >> 4) * 4;            // producer row base; valid if < 8
  const bool pvalid = (l64 < 32);
  const int F0 = rank * FPW + w * 16;        // this wave's 16 output feats
  const int Fl = F0 + l15;
  const int rr = tid >> 5;                   // consumer row 0..7
  const int cc = tid & 31;                   // consumer 16-feat chunk

  // ---- weights -> registers: full K=512 for 16 feats per wave ----
  short8 wr[16], wt[16];
#pragma unroll
  for (int kc = 0; kc < 16; kc++){
    const int k = kc * 32 + q * 8;
    wr[kc] = cvt8(&W_rec[(size_t)Fl * H_DIM + k]);
    wt[kc] = cvt8(&tau_w1[(size_t)Fl * (I_DIM + H_DIM) + I_DIM + k]);
  }
  const float tw2v = tau_w2[Fl];
  const float tb2 = tau_b2_p[0];

  // ---- consumer state: h, gamma, beta in registers ----
  float h_reg[16], gamr[16], betr[16];
  {
    const int b = cl * ROWS + rr;
#pragma unroll
    for (int j = 0; j < 16; j++){
      float hv = h0[(size_t)b * H_DIM + cc * 16 + j];
      h_reg[j] = hv;
      hB[rr * HSTR + cc * 16 + j] = f2bf(hv);
      gamr[j] = gamma[cc * 16 + j];
      betr[j] = beta[cc * 16 + j];
    }
  }

  // prefetch A terms for t=0 (producer layout: 4 consecutive rows per lane)
  ushortx4 afr = (ushortx4){0,0,0,0}, atr = (ushortx4){0,0,0,0};
  if (pvalid){
    const size_t aidx = ((size_t)Fl) * BATCH + cl * ROWS + rb0;
    afr = *(const ushortx4*)&A_in[aidx];
    atr = *(const ushortx4*)&A_tau[aidx];
  }
  __syncthreads();

  for (int t = 0; t < S_LEN; t++){
    const int par = t & 1;

    // ---- producer: full-K matvec, 16 feats x 8 rows (rows 8..15 are zero pad)
    floatx4 af = {0,0,0,0}, at4 = {0,0,0,0};
#pragma unroll
    for (int kc = 0; kc < 16; kc++){
      short8 ha = *(const short8*)&hB[l15 * HSTR + kc * 32 + q * 8];
      af  = __builtin_amdgcn_mfma_f32_16x16x32_bf16(ha, wr[kc], af,  0, 0, 0);
      at4 = __builtin_amdgcn_mfma_f32_16x16x32_bf16(ha, wt[kc], at4, 0, 0, 0);
    }

    // epilogue: tanh, broadcast f (packed bf16 pairs), tau partial dot
    unsigned short* bcF = bc_f + ((size_t)(par * NCL + cl) * ROWS) * H_DIM;
    float pd[4];
#pragma unroll
    for (int i2 = 0; i2 < 4; i2++){
      float vf = fast_tanh(af[i2]  + bf2f(afr[i2]));
      float vt = fast_tanh(at4[i2] + bf2f(atr[i2]));
      pd[i2] = vt * tw2v;
      unsigned pv = (unsigned)f2bf(vf);
      unsigned ov = (unsigned)__shfl_xor((int)pv, 1);
      if (pvalid && !(fl & 1)){
        unsigned short* p = bcF + (size_t)(rb0 + i2) * H_DIM + F0 + fl;
        st_u32(p, pv | (ov << 16), fast);
      }
    }
#pragma unroll
    for (int i2 = 0; i2 < 4; i2++){
      pd[i2] += __shfl_xor(pd[i2], 1);
      pd[i2] += __shfl_xor(pd[i2], 2);
      pd[i2] += __shfl_xor(pd[i2], 4);
      pd[i2] += __shfl_xor(pd[i2], 8);
    }
    if (pvalid && fl == 0){
      floatx4 v4 = {pd[0], pd[1], pd[2], pd[3]};
      float* p = bc_td + ((size_t)(par * NCL + cl) * 32 + rank * 4 + w) * ROWS + rb0;
      st_f128(p, v4, fast);
    }

    // drain own stores (per wave), then store-only arrival flag
    asm volatile("s_waitcnt vmcnt(0)" ::: "memory");
    __syncthreads();
    if (tid == 0) st_u32(&flags[cl * NRK + rank], (unsigned)(t + 1), fast);
    if (w == 0 && l64 < NRK){
      const unsigned tgt = (unsigned)(t + 1);
      const unsigned int* fp = &flags[cl * NRK + l64];
      int guard = 0;
      for (;;){
        unsigned v = ld_flag(fp, fast);
        if (v >= tgt || ++guard > POLL_CAP) break;   // cap: fail visibly, never hang
        __builtin_amdgcn_s_sleep(1);
      }
    }
    __syncthreads();

    // ---- consumer: readback full f slice + tau partials (one wait) ----
    const unsigned short* rbF =
      bc_f + (((size_t)(par * NCL + cl) * ROWS) + rr) * H_DIM + cc * 16;
    const float* tdp = bc_td + ((size_t)(par * NCL + cl) * 32 + cc) * ROWS + rr;
    short8 r0, r1; float tdv;
    if (fast){
      asm volatile(
        "global_load_dwordx4 %0, %3, off sc0\n\t"
        "global_load_dwordx4 %1, %4, off sc0\n\t"
        "global_load_dword %2, %5, off sc0\n\t"
        "s_waitcnt vmcnt(0)"
        : "=&v"(r0), "=&v"(r1), "=&v"(tdv)
        : "v"(rbF), "v"(rbF + 8), "v"(tdp) : "memory");
    } else {
      asm volatile(
        "global_load_dwordx4 %0, %3, off sc1\n\t"
        "global_load_dwordx4 %1, %4, off sc1\n\t"
        "global_load_dword %2, %5, off sc1\n\t"
        "s_waitcnt vmcnt(0)"
        : "=&v"(r0), "=&v"(r1), "=&v"(tdv)
        : "v"(rbF), "v"(rbF + 8), "v"(tdp) : "memory");
    }

    float td = tdv;
    td += __shfl_xor(td, 1); td += __shfl_xor(td, 2);
    td += __shfl_xor(td, 4); td += __shfl_xor(td, 8);
    td += __shfl_xor(td, 16);
    const float tau = 1.0f + 9.0f * fast_sigmoid(td + tb2);
    const float c2 = 0.1f / tau, c1 = 1.0f - c2;

    // prefetch A for t+1 (plain cached loads; latency hides under LN)
    if (t + 1 < S_LEN && pvalid){
      const size_t aidx = ((size_t)(t + 1) * H_DIM + Fl) * BATCH + cl * ROWS + rb0;
      afr = *(const ushortx4*)&A_in[aidx];
      atr = *(const ushortx4*)&A_tau[aidx];
    }

    float fv[16];
#pragma unroll
    for (int e = 0; e < 8; e++){
      fv[e]     = bf2f((unsigned short)r0[e]);
      fv[8 + e] = bf2f((unsigned short)r1[e]);
    }
    float hp[16]; float s1 = 0.f, s2 = 0.f;
#pragma unroll
    for (int j = 0; j < 16; j++){
      float v2 = c1 * h_reg[j] + c2 * fv[j];
      hp[j] = v2; s1 += v2; s2 += v2 * v2;
    }
    s1 += __shfl_xor(s1, 1);  s2 += __shfl_xor(s2, 1);
    s1 += __shfl_xor(s1, 2);  s2 += __shfl_xor(s2, 2);
    s1 += __shfl_xor(s1, 4);  s2 += __shfl_xor(s2, 4);
    s1 += __shfl_xor(s1, 8);  s2 += __shfl_xor(s2, 8);
    s1 += __shfl_xor(s1, 16); s2 += __shfl_xor(s2, 16);
    const float mu = s1 * (1.0f / 512.0f);
    const float var = s2 * (1.0f / 512.0f) - mu * mu;
    const float rs = rsqrtf(var + 1e-5f);
#pragma unroll
    for (int j = 0; j < 16; j++) h_reg[j] = (hp[j] - mu) * rs * gamr[j] + betr[j];

    // h -> LDS bf16 for next matvec
#pragma unroll
    for (int u = 0; u < 2; u++){
      short8 hv;
#pragma unroll
      for (int e = 0; e < 8; e++) hv[e] = (short)f2bf(h_reg[u * 8 + e]);
      *(short8*)&hB[rr * HSTR + cc * 16 + u * 8] = hv;
    }

    // outputs: rank r owns batch row rr == r (each row written exactly once)
    if (rr == rank){
      float* dst = out0 + ((size_t)(cl * ROWS + rr) * S_LEN + t) * H_DIM + cc * 16;
#pragma unroll
      for (int j = 0; j < 16; j++) dst[j] = h_reg[j];
      if (cc == 0) outtau[(size_t)(cl * ROWS + rr) * S_LEN + t] = tau;
      if (t == S_LEN - 1){
        float* dh = outh + (size_t)(cl * ROWS + rr) * H_DIM + cc * 16;
#pragma unroll
        for (int j = 0; j < 16; j++) dh[j] = h_reg[j];
      }
    }
    __syncthreads();
  }
}

extern "C" void kernel_launch(void* const* d_in, const int* in_sizes, int n_in,
                              void* d_out, int out_size, void* d_ws, size_t ws_size,
                              hipStream_t stream) {
  const float* x      = (const float*)d_in[0];
  const float* h0     = (const float*)d_in[1];
  const float* W_in   = (const float*)d_in[2];
  const float* b_in   = (const float*)d_in[3];
  const float* W_rec  = (const float*)d_in[4];
  const float* tau_w1 = (const float*)d_in[5];
  const float* tau_b1 = (const float*)d_in[6];
  const float* tau_w2 = (const float*)d_in[7];
  const float* tau_b2 = (const float*)d_in[8];
  const float* gamma  = (const float*)d_in[9];
  const float* beta   = (const float*)d_in[10];

  char* ws = (char*)d_ws;
  unsigned short* A_in   = (unsigned short*)(ws);                 // 67,108,864 B
  unsigned short* A_tau  = (unsigned short*)(ws + 67108864);      // 67,108,864 B
  unsigned short* bc_f   = (unsigned short*)(ws + 134217728);     // 131,072 B
  float*          bc_td  = (float*)(ws + 134348800);              // 16,384 B
  unsigned int*   flags  = (unsigned int*)(ws + 134365184);       // 1,024 B (flags+handshake)
  unsigned short* Wbf    = (unsigned short*)(ws + 134366208);     // 262,144 B
  unsigned short* Tbf    = (unsigned short*)(ws + 134628352);     // 262,144 B

  float* out0   = (float*)d_out;
  float* outh   = out0 + (size_t)BATCH * S_LEN * H_DIM;           // 33,554,432
  float* outtau = outh + (size_t)BATCH * H_DIM;                   // +32,768

  hipMemsetAsync(flags, 0, 1024, stream);
  convert_weights_kernel<<<dim3(H_DIM), 256, 0, stream>>>(W_in, tau_w1, Wbf, Tbf);
  precompute_kernel<<<dim3(S_LEN), 256, 0, stream>>>(x, Wbf, Tbf, b_in, tau_b1, A_in, A_tau);
  scan_kernel<<<dim3(NCL * NRK), 256, 0, stream>>>(h0, W_rec, tau_w1, tau_w2, tau_b2, gamma, beta,
                                                   A_in, A_tau, bc_f, bc_td, flags,
                                                   out0, outh, outtau);
}

// Round 3
// 24416.713 us; speedup vs baseline: 80.4996x; 80.4996x over previous
//
#include <hip/hip_runtime.h>

#define S_LEN 1024
#define BATCH 64
#define I_DIM 256
#define H_DIM 512
#define NCL 8      // clusters (8 batch rows each)
#define NRK 8      // WGs per cluster (64 feats each)
#define ROWS 8
#define FPW 64     // feats per WG (16 per wave, full K per wave)
#define HSTR 520   // LDS row stride (bf16 elems) for h
#define XSTR 264   // LDS row stride (bf16) for x staging in precompute
#define POLL_CAP 16384
#define HSHAKE_CAP 200000
#define TRIAL_CAP 131072

typedef short short8 __attribute__((ext_vector_type(8)));
typedef float floatx4 __attribute__((ext_vector_type(4)));
typedef unsigned short ushortx4 __attribute__((ext_vector_type(4)));

__device__ inline unsigned short f2bf(float x){
  unsigned u = __float_as_uint(x);
  u += 0x7fffu + ((u >> 16) & 1u);           // RNE
  return (unsigned short)(u >> 16);
}
__device__ inline float bf2f(unsigned short s){
  return __uint_as_float(((unsigned)s) << 16);
}
__device__ inline float fast_tanh(float x){
  float e = __expf(2.0f * x);                // inf-safe: +inf -> 1, 0 -> -1
  return 1.0f - 2.0f / (e + 1.0f);
}
__device__ inline float fast_sigmoid(float x){
  return 1.0f / (1.0f + __expf(-x));
}
__device__ inline short8 cvt8(const float* p){
  short8 r;
#pragma unroll
  for (int j = 0; j < 8; j++) r[j] = (short)f2bf(p[j]);
  return r;
}

// ---- scoped comm helpers.
// gfx950 cache bits are PER-LEVEL: SC0 -> L1 (set = bypass/miss L1),
// SC1 -> L2 (set = bypass / write-through L2).
// fast (XCD-local, via shared per-XCD L2):  sc0
// slow (device scope, via L3 coherence pt): sc0 sc1   (round-2 bug: sc1-only
// left L1 lookup enabled -> stale flag line -> POLL_CAP every step)
__device__ inline void st_u32(void* p, unsigned v, bool fast){
  if (fast) asm volatile("global_store_dword %0, %1, off sc0" :: "v"(p), "v"(v) : "memory");
  else      asm volatile("global_store_dword %0, %1, off sc0 sc1" :: "v"(p), "v"(v) : "memory");
}
__device__ inline void st_f128(void* p, floatx4 v, bool fast){
  if (fast) asm volatile("global_store_dwordx4 %0, %1, off sc0" :: "v"(p), "v"(v) : "memory");
  else      asm volatile("global_store_dwordx4 %0, %1, off sc0 sc1" :: "v"(p), "v"(v) : "memory");
}
__device__ inline unsigned ld_flag(const void* p, bool fast){
  unsigned v;
  if (fast) asm volatile("global_load_dword %0, %1, off sc0\n\ts_waitcnt vmcnt(0)"
                         : "=&v"(v) : "v"(p) : "memory");
  else      asm volatile("global_load_dword %0, %1, off sc0 sc1\n\ts_waitcnt vmcnt(0)"
                         : "=&v"(v) : "v"(p) : "memory");
  return v;
}

// ---------------------------------------------------------------------------
// Kernel W: pre-convert W_in and tau_w1[:, :256] to bf16. (unchanged)
// ---------------------------------------------------------------------------
__global__ __launch_bounds__(256) void convert_weights_kernel(
  const float* __restrict__ W_in, const float* __restrict__ tau_w1,
  unsigned short* __restrict__ Wbf, unsigned short* __restrict__ Tbf)
{
  const int f = blockIdx.x, k = threadIdx.x;
  Wbf[f * I_DIM + k] = f2bf(W_in[(size_t)f * I_DIM + k]);
  Tbf[f * I_DIM + k] = f2bf(tau_w1[(size_t)f * (I_DIM + H_DIM) + k]);
}

// ---------------------------------------------------------------------------
// Kernel P: A_in[t][F][b], A_tau[t][F][b]  (unchanged)
// ---------------------------------------------------------------------------
__global__ __launch_bounds__(256) void precompute_kernel(
  const float* __restrict__ x, const unsigned short* __restrict__ Wbf,
  const unsigned short* __restrict__ Tbf,
  const float* __restrict__ b_in, const float* __restrict__ tau_b1,
  unsigned short* __restrict__ A_in, unsigned short* __restrict__ A_tau)
{
  __shared__ unsigned short xs[BATCH * XSTR];
  const int t = blockIdx.x, tid = threadIdx.x;
  {
    const int br = tid >> 2, pp = tid & 3;
    const float* xrow = x + ((size_t)br * S_LEN + t) * I_DIM + pp * 64;
    unsigned short* drow = xs + br * XSTR + pp * 64;
#pragma unroll
    for (int c = 0; c < 16; c++){
      float4 v = *(const float4*)(xrow + c * 4);
      ushortx4 o; o[0] = f2bf(v.x); o[1] = f2bf(v.y); o[2] = f2bf(v.z); o[3] = f2bf(v.w);
      *(ushortx4*)(drow + c * 4) = o;
    }
  }
  __syncthreads();

  const int w = tid >> 6, l15 = tid & 15, q = (tid & 63) >> 4;
#pragma unroll 1
  for (int fb = 0; fb < 8; fb++){
    const int F = fb * 64 + w * 16 + l15;
    floatx4 accf[4], acct[4];
#pragma unroll
    for (int m = 0; m < 4; m++){ accf[m] = (floatx4){0,0,0,0}; acct[m] = (floatx4){0,0,0,0}; }
#pragma unroll
    for (int kc = 0; kc < 8; kc++){
      const int k0 = kc * 32 + q * 8;
      short8 bw = *(const short8*)&Wbf[F * I_DIM + k0];
      short8 bt = *(const short8*)&Tbf[F * I_DIM + k0];
#pragma unroll
      for (int m = 0; m < 4; m++){
        short8 a = *(const short8*)&xs[(m * 16 + l15) * XSTR + k0];
        accf[m] = __builtin_amdgcn_mfma_f32_16x16x32_bf16(a, bw, accf[m], 0, 0, 0);
        acct[m] = __builtin_amdgcn_mfma_f32_16x16x32_bf16(a, bt, acct[m], 0, 0, 0);
      }
    }
    const float bi = b_in[F], bt1 = tau_b1[F];
#pragma unroll
    for (int m = 0; m < 4; m++){
      ushortx4 pf, pt;
#pragma unroll
      for (int i2 = 0; i2 < 4; i2++){ pf[i2] = f2bf(accf[m][i2] + bi); pt[i2] = f2bf(acct[m][i2] + bt1); }
      const size_t base = ((size_t)t * H_DIM + F) * BATCH + m * 16 + q * 4;
      *(ushortx4*)(A_in + base) = pf;
      *(ushortx4*)(A_tau + base) = pt;
    }
  }
}

// ---------------------------------------------------------------------------
// Kernel S: persistent scan, XCD-local clusters.
//   Handshake: group WGs by HW_REG_XCC_ID; any placement with per-XCD counts
//   that are multiples of 8 forms clusters (prefix-sum mapping). Then a
//   two-phase ping-pong TRIAL on the real sc0 comm path verifies XCD-local
//   visibility (phase 2 re-reads a line phase 1 cached -> catches any stale-L1
//   scenario). On any doubt: global demote -> device-scope (sc0 sc1) comm.
//   Flag indices: 0..63 step flags | 64..71 initcnt | 80 g_cnt | 81 g_cnt2 |
//   82 demote | 96..159 trial. Host memsets 1024 B each launch.
// ---------------------------------------------------------------------------
__global__ __launch_bounds__(256, 1) void scan_kernel(
  const float* __restrict__ h0, const float* __restrict__ W_rec,
  const float* __restrict__ tau_w1, const float* __restrict__ tau_w2,
  const float* __restrict__ tau_b2_p, const float* __restrict__ gamma,
  const float* __restrict__ beta,
  const unsigned short* __restrict__ A_in, const unsigned short* __restrict__ A_tau,
  unsigned short* __restrict__ bc_f, float* __restrict__ bc_td,
  unsigned int* __restrict__ flags,
  float* __restrict__ out0, float* __restrict__ outh, float* __restrict__ outtau)
{
  __shared__ unsigned short hB[16 * HSTR];   // rows 8..15 stay zero (MFMA M=16 pad)
  __shared__ int sh_cl, sh_rk, sh_fast;

  const int tid = threadIdx.x;

  // ---- phase 1: discover XCD, form clusters ----
  if (tid == 0){
    unsigned xcd;
    asm volatile("s_getreg_b32 %0, hwreg(HW_REG_XCC_ID)" : "=s"(xcd));
    xcd &= 7u;
    unsigned* initcnt = flags + 64;
    unsigned* g_cnt   = flags + 80;
    int slot = atomicAdd((int*)&initcnt[xcd], 1);
    __builtin_amdgcn_s_waitcnt(0);    // initcnt RMW globally visible before g_cnt RMW
    atomicAdd((int*)g_cnt, 1);
    unsigned seen = 0; int hcap = 0;
    for (;;){
      seen = __hip_atomic_load(g_cnt, __ATOMIC_RELAXED, __HIP_MEMORY_SCOPE_AGENT);
      if (seen >= 64u || ++hcap > HSHAKE_CAP) break;
      __builtin_amdgcn_s_sleep(8);
    }
    int ok = (seen >= 64u) ? 1 : 0;
    unsigned c8[8]; int pre = 0;
#pragma unroll
    for (int x2 = 0; x2 < 8; x2++){
      c8[x2] = __hip_atomic_load(&initcnt[x2], __ATOMIC_RELAXED, __HIP_MEMORY_SCOPE_AGENT);
      ok &= ((c8[x2] & 7u) == 0u);     // need multiples of 8 per XCD
    }
    for (unsigned y = 0; y < xcd; y++) pre += (int)(c8[y] >> 3);
    if (ok){ sh_cl = pre + (slot >> 3); sh_rk = slot & 7; sh_fast = 1; }
    else   { sh_cl = (int)(blockIdx.x & 7); sh_rk = (int)(blockIdx.x >> 3); sh_fast = 0; }
  }
  for (int idx = tid; idx < 16 * HSTR; idx += 256) hB[idx] = 0;
  __syncthreads();
  const int cl = sh_cl, rank = sh_rk;

  // ---- phase 2: two-phase ping-pong trial of sc0 comm within cluster ----
  if (sh_fast){
    unsigned int* myTrial = &flags[96 + cl * 8 + rank];
    if (tid == 0) st_u32(myTrial, 1u, true);
    if (tid < 8){
      int guard = 0;
      for (;;){
        unsigned v = ld_flag(&flags[96 + cl * 8 + tid], true);
        if (v >= 1u) break;
        if (++guard > TRIAL_CAP){ atomicExch((int*)&flags[82], 1); break; }
        __builtin_amdgcn_s_sleep(1);
      }
    }
    // phase 2: same addresses again — catches an L1-resident stale line
    if (tid == 0) st_u32(myTrial, 2u, true);
    if (tid < 8){
      int guard = 0;
      for (;;){
        unsigned v = ld_flag(&flags[96 + cl * 8 + tid], true);
        if (v >= 2u) break;
        if (++guard > TRIAL_CAP){ atomicExch((int*)&flags[82], 1); break; }
        __builtin_amdgcn_s_sleep(1);
      }
    }
    __syncthreads();
  }
  // ---- phase 3: device barrier, then read global demote flag ----
  if (tid == 0){
    atomicAdd((int*)&flags[81], 1);
    unsigned seen2 = 0; int hcap2 = 0;
    for (;;){
      seen2 = __hip_atomic_load(&flags[81], __ATOMIC_RELAXED, __HIP_MEMORY_SCOPE_AGENT);
      if (seen2 >= 64u || ++hcap2 > HSHAKE_CAP) break;
      __builtin_amdgcn_s_sleep(8);
    }
    unsigned dm = __hip_atomic_load(&flags[82], __ATOMIC_RELAXED, __HIP_MEMORY_SCOPE_AGENT);
    if (seen2 < 64u) dm = 1u;
    if (dm) sh_fast = 0;
  }
  __syncthreads();
  const bool fast = (sh_fast != 0);

  const int w = tid >> 6, l64 = tid & 63, l15 = tid & 15, q = (tid & 63) >> 4;
  const int fl = l15;
  const int rb0 = (l64 >> 4) * 4;            // producer row base; valid if < 8
  const bool pvalid = (l64 < 32);
  const int F0 = rank * FPW + w * 16;        // this wave's 16 output feats
  const int Fl = F0 + l15;
  const int rr = tid >> 5;                   // consumer row 0..7
  const int cc = tid & 31;                   // consumer 16-feat chunk

  // ---- weights -> registers: full K=512 for 16 feats per wave ----
  short8 wr[16], wt[16];
#pragma unroll
  for (int kc = 0; kc < 16; kc++){
    const int k = kc * 32 + q * 8;
    wr[kc] = cvt8(&W_rec[(size_t)Fl * H_DIM + k]);
    wt[kc] = cvt8(&tau_w1[(size_t)Fl * (I_DIM + H_DIM) + I_DIM + k]);
  }
  const float tw2v = tau_w2[Fl];
  const float tb2 = tau_b2_p[0];

  // ---- consumer state: h, gamma, beta in registers ----
  float h_reg[16], gamr[16], betr[16];
  {
    const int b = cl * ROWS + rr;
#pragma unroll
    for (int j = 0; j < 16; j++){
      float hv = h0[(size_t)b * H_DIM + cc * 16 + j];
      h_reg[j] = hv;
      hB[rr * HSTR + cc * 16 + j] = f2bf(hv);
      gamr[j] = gamma[cc * 16 + j];
      betr[j] = beta[cc * 16 + j];
    }
  }

  // prefetch A terms for t=0 (producer layout: 4 consecutive rows per lane)
  ushortx4 afr = (ushortx4){0,0,0,0}, atr = (ushortx4){0,0,0,0};
  if (pvalid){
    const size_t aidx = ((size_t)Fl) * BATCH + cl * ROWS + rb0;
    afr = *(const ushortx4*)&A_in[aidx];
    atr = *(const ushortx4*)&A_tau[aidx];
  }
  __syncthreads();

  for (int t = 0; t < S_LEN; t++){
    const int par = t & 1;

    // ---- producer: full-K matvec, 16 feats x 8 rows (rows 8..15 zero pad)
    floatx4 af = {0,0,0,0}, at4 = {0,0,0,0};
#pragma unroll
    for (int kc = 0; kc < 16; kc++){
      short8 ha = *(const short8*)&hB[l15 * HSTR + kc * 32 + q * 8];
      af  = __builtin_amdgcn_mfma_f32_16x16x32_bf16(ha, wr[kc], af,  0, 0, 0);
      at4 = __builtin_amdgcn_mfma_f32_16x16x32_bf16(ha, wt[kc], at4, 0, 0, 0);
    }

    // epilogue: tanh, broadcast f (packed bf16 pairs), tau partial dot
    unsigned short* bcF = bc_f + ((size_t)(par * NCL + cl) * ROWS) * H_DIM;
    float pd[4];
#pragma unroll
    for (int i2 = 0; i2 < 4; i2++){
      float vf = fast_tanh(af[i2]  + bf2f(afr[i2]));
      float vt = fast_tanh(at4[i2] + bf2f(atr[i2]));
      pd[i2] = vt * tw2v;
      unsigned pv = (unsigned)f2bf(vf);
      unsigned ov = (unsigned)__shfl_xor((int)pv, 1);
      if (pvalid && !(fl & 1)){
        unsigned short* p = bcF + (size_t)(rb0 + i2) * H_DIM + F0 + fl;
        st_u32(p, pv | (ov << 16), fast);
      }
    }
#pragma unroll
    for (int i2 = 0; i2 < 4; i2++){
      pd[i2] += __shfl_xor(pd[i2], 1);
      pd[i2] += __shfl_xor(pd[i2], 2);
      pd[i2] += __shfl_xor(pd[i2], 4);
      pd[i2] += __shfl_xor(pd[i2], 8);
    }
    if (pvalid && fl == 0){
      floatx4 v4 = {pd[0], pd[1], pd[2], pd[3]};
      float* p = bc_td + ((size_t)(par * NCL + cl) * 32 + rank * 4 + w) * ROWS + rb0;
      st_f128(p, v4, fast);
    }

    // drain own stores, then store-only arrival flag
    asm volatile("s_waitcnt vmcnt(0)" ::: "memory");
    __syncthreads();
    if (tid == 0) st_u32(&flags[cl * NRK + rank], (unsigned)(t + 1), fast);
    if (w == 0 && l64 < NRK){
      const unsigned tgt = (unsigned)(t + 1);
      const unsigned int* fp = &flags[cl * NRK + l64];
      int guard = 0;
      for (;;){
        unsigned v = ld_flag(fp, fast);
        if (v >= tgt || ++guard > POLL_CAP) break;   // cap: fail visibly, never hang
        __builtin_amdgcn_s_sleep(1);
      }
    }
    __syncthreads();

    // ---- consumer: readback full f slice + tau partials (one wait) ----
    const unsigned short* rbF =
      bc_f + (((size_t)(par * NCL + cl) * ROWS) + rr) * H_DIM + cc * 16;
    const float* tdp = bc_td + ((size_t)(par * NCL + cl) * 32 + cc) * ROWS + rr;
    short8 r0, r1; float tdv;
    if (fast){
      asm volatile(
        "global_load_dwordx4 %0, %3, off sc0\n\t"
        "global_load_dwordx4 %1, %4, off sc0\n\t"
        "global_load_dword %2, %5, off sc0\n\t"
        "s_waitcnt vmcnt(0)"
        : "=&v"(r0), "=&v"(r1), "=&v"(tdv)
        : "v"(rbF), "v"(rbF + 8), "v"(tdp) : "memory");
    } else {
      asm volatile(
        "global_load_dwordx4 %0, %3, off sc0 sc1\n\t"
        "global_load_dwordx4 %1, %4, off sc0 sc1\n\t"
        "global_load_dword %2, %5, off sc0 sc1\n\t"
        "s_waitcnt vmcnt(0)"
        : "=&v"(r0), "=&v"(r1), "=&v"(tdv)
        : "v"(rbF), "v"(rbF + 8), "v"(tdp) : "memory");
    }

    float td = tdv;
    td += __shfl_xor(td, 1); td += __shfl_xor(td, 2);
    td += __shfl_xor(td, 4); td += __shfl_xor(td, 8);
    td += __shfl_xor(td, 16);
    const float tau = 1.0f + 9.0f * fast_sigmoid(td + tb2);
    const float c2 = 0.1f / tau, c1 = 1.0f - c2;

    // prefetch A for t+1 (plain cached loads; latency hides under LN)
    if (t + 1 < S_LEN && pvalid){
      const size_t aidx = ((size_t)(t + 1) * H_DIM + Fl) * BATCH + cl * ROWS + rb0;
      afr = *(const ushortx4*)&A_in[aidx];
      atr = *(const ushortx4*)&A_tau[aidx];
    }

    float fv[16];
#pragma unroll
    for (int e = 0; e < 8; e++){
      fv[e]     = bf2f((unsigned short)r0[e]);
      fv[8 + e] = bf2f((unsigned short)r1[e]);
    }
    float hp[16]; float s1 = 0.f, s2 = 0.f;
#pragma unroll
    for (int j = 0; j < 16; j++){
      float v2 = c1 * h_reg[j] + c2 * fv[j];
      hp[j] = v2; s1 += v2; s2 += v2 * v2;
    }
    s1 += __shfl_xor(s1, 1);  s2 += __shfl_xor(s2, 1);
    s1 += __shfl_xor(s1, 2);  s2 += __shfl_xor(s2, 2);
    s1 += __shfl_xor(s1, 4);  s2 += __shfl_xor(s2, 4);
    s1 += __shfl_xor(s1, 8);  s2 += __shfl_xor(s2, 8);
    s1 += __shfl_xor(s1, 16); s2 += __shfl_xor(s2, 16);
    const float mu = s1 * (1.0f / 512.0f);
    const float var = s2 * (1.0f / 512.0f) - mu * mu;
    const float rs = rsqrtf(var + 1e-5f);
#pragma unroll
    for (int j = 0; j < 16; j++) h_reg[j] = (hp[j] - mu) * rs * gamr[j] + betr[j];

    // h -> LDS bf16 for next matvec
#pragma unroll
    for (int u = 0; u < 2; u++){
      short8 hv;
#pragma unroll
      for (int e = 0; e < 8; e++) hv[e] = (short)f2bf(h_reg[u * 8 + e]);
      *(short8*)&hB[rr * HSTR + cc * 16 + u * 8] = hv;
    }

    // outputs: rank r owns batch row rr == r (each row written exactly once)
    if (rr == rank){
      float* dst = out0 + ((size_t)(cl * ROWS + rr) * S_LEN + t) * H_DIM + cc * 16;
#pragma unroll
      for (int j = 0; j < 16; j++) dst[j] = h_reg[j];
      if (cc == 0) outtau[(size_t)(cl * ROWS + rr) * S_LEN + t] = tau;
      if (t == S_LEN - 1){
        float* dh = outh + (size_t)(cl * ROWS + rr) * H_DIM + cc * 16;
#pragma unroll
        for (int j = 0; j < 16; j++) dh[j] = h_reg[j];
      }
    }
    __syncthreads();
  }
}

extern "C" void kernel_launch(void* const* d_in, const int* in_sizes, int n_in,
                              void* d_out, int out_size, void* d_ws, size_t ws_size,
                              hipStream_t stream) {
  const float* x      = (const float*)d_in[0];
  const float* h0     = (const float*)d_in[1];
  const float* W_in   = (const float*)d_in[2];
  const float* b_in   = (const float*)d_in[3];
  const float* W_rec  = (const float*)d_in[4];
  const float* tau_w1 = (const float*)d_in[5];
  const float* tau_b1 = (const float*)d_in[6];
  const float* tau_w2 = (const float*)d_in[7];
  const float* tau_b2 = (const float*)d_in[8];
  const float* gamma  = (const float*)d_in[9];
  const float* beta   = (const float*)d_in[10];

  char* ws = (char*)d_ws;
  unsigned short* A_in   = (unsigned short*)(ws);                 // 67,108,864 B
  unsigned short* A_tau  = (unsigned short*)(ws + 67108864);      // 67,108,864 B
  unsigned short* bc_f   = (unsigned short*)(ws + 134217728);     // 131,072 B
  float*          bc_td  = (float*)(ws + 134348800);              // 16,384 B
  unsigned int*   flags  = (unsigned int*)(ws + 134365184);       // 1,024 B (flags+handshake+trial)
  unsigned short* Wbf    = (unsigned short*)(ws + 134366208);     // 262,144 B
  unsigned short* Tbf    = (unsigned short*)(ws + 134628352);     // 262,144 B

  float* out0   = (float*)d_out;
  float* outh   = out0 + (size_t)BATCH * S_LEN * H_DIM;           // 33,554,432
  float* outtau = outh + (size_t)BATCH * H_DIM;                   // +32,768

  hipMemsetAsync(flags, 0, 1024, stream);
  convert_weights_kernel<<<dim3(H_DIM), 256, 0, stream>>>(W_in, tau_w1, Wbf, Tbf);
  precompute_kernel<<<dim3(S_LEN), 256, 0, stream>>>(x, Wbf, Tbf, b_in, tau_b1, A_in, A_tau);
  scan_kernel<<<dim3(NCL * NRK), 256, 0, stream>>>(h0, W_rec, tau_w1, tau_w2, tau_b2, gamma, beta,
                                                   A_in, A_tau, bc_f, bc_td, flags,
                                                   out0, outh, outtau);
}

// Round 4
// 4367.907 us; speedup vs baseline: 449.9947x; 5.5900x over previous
//
#include <hip/hip_runtime.h>

#define S_LEN 1024
#define BATCH 64
#define I_DIM 256
#define H_DIM 512
#define NCL 8      // clusters (8 batch rows each)
#define NRK 8      // WGs per cluster (64 feats each)
#define ROWS 8
#define FPW 64     // feats per WG (16 per wave, full K per wave)
#define HSTR 520   // LDS row stride (bf16 elems) for h
#define XSTR 264   // LDS row stride (bf16) for x staging in precompute
#define POLL_CAP 16384

typedef short short8 __attribute__((ext_vector_type(8)));
typedef float floatx4 __attribute__((ext_vector_type(4)));
typedef unsigned short ushortx4 __attribute__((ext_vector_type(4)));

__device__ inline unsigned short f2bf(float x){
  unsigned u = __float_as_uint(x);
  u += 0x7fffu + ((u >> 16) & 1u);           // RNE
  return (unsigned short)(u >> 16);
}
__device__ inline float bf2f(unsigned short s){
  return __uint_as_float(((unsigned)s) << 16);
}
__device__ inline float fast_tanh(float x){
  float e = __expf(2.0f * x);                // inf-safe: +inf -> 1, 0 -> -1
  return 1.0f - 2.0f / (e + 1.0f);
}
__device__ inline float fast_sigmoid(float x){
  return 1.0f / (1.0f + __expf(-x));
}
__device__ inline short8 cvt8(const float* p){
  short8 r;
#pragma unroll
  for (int j = 0; j < 8; j++) r[j] = (short)f2bf(p[j]);
  return r;
}

// ---------------------------------------------------------------------------
// Kernel W: pre-convert W_in and tau_w1[:, :256] to bf16. (unchanged)
// ---------------------------------------------------------------------------
__global__ __launch_bounds__(256) void convert_weights_kernel(
  const float* __restrict__ W_in, const float* __restrict__ tau_w1,
  unsigned short* __restrict__ Wbf, unsigned short* __restrict__ Tbf)
{
  const int f = blockIdx.x, k = threadIdx.x;
  Wbf[f * I_DIM + k] = f2bf(W_in[(size_t)f * I_DIM + k]);
  Tbf[f * I_DIM + k] = f2bf(tau_w1[(size_t)f * (I_DIM + H_DIM) + k]);
}

// ---------------------------------------------------------------------------
// Kernel P: A_in[t][F][b], A_tau[t][F][b]  (unchanged)
// ---------------------------------------------------------------------------
__global__ __launch_bounds__(256) void precompute_kernel(
  const float* __restrict__ x, const unsigned short* __restrict__ Wbf,
  const unsigned short* __restrict__ Tbf,
  const float* __restrict__ b_in, const float* __restrict__ tau_b1,
  unsigned short* __restrict__ A_in, unsigned short* __restrict__ A_tau)
{
  __shared__ unsigned short xs[BATCH * XSTR];
  const int t = blockIdx.x, tid = threadIdx.x;
  {
    const int br = tid >> 2, pp = tid & 3;
    const float* xrow = x + ((size_t)br * S_LEN + t) * I_DIM + pp * 64;
    unsigned short* drow = xs + br * XSTR + pp * 64;
#pragma unroll
    for (int c = 0; c < 16; c++){
      float4 v = *(const float4*)(xrow + c * 4);
      ushortx4 o; o[0] = f2bf(v.x); o[1] = f2bf(v.y); o[2] = f2bf(v.z); o[3] = f2bf(v.w);
      *(ushortx4*)(drow + c * 4) = o;
    }
  }
  __syncthreads();

  const int w = tid >> 6, l15 = tid & 15, q = (tid & 63) >> 4;
#pragma unroll 1
  for (int fb = 0; fb < 8; fb++){
    const int F = fb * 64 + w * 16 + l15;
    floatx4 accf[4], acct[4];
#pragma unroll
    for (int m = 0; m < 4; m++){ accf[m] = (floatx4){0,0,0,0}; acct[m] = (floatx4){0,0,0,0}; }
#pragma unroll
    for (int kc = 0; kc < 8; kc++){
      const int k0 = kc * 32 + q * 8;
      short8 bw = *(const short8*)&Wbf[F * I_DIM + k0];
      short8 bt = *(const short8*)&Tbf[F * I_DIM + k0];
#pragma unroll
      for (int m = 0; m < 4; m++){
        short8 a = *(const short8*)&xs[(m * 16 + l15) * XSTR + k0];
        accf[m] = __builtin_amdgcn_mfma_f32_16x16x32_bf16(a, bw, accf[m], 0, 0, 0);
        acct[m] = __builtin_amdgcn_mfma_f32_16x16x32_bf16(a, bt, acct[m], 0, 0, 0);
      }
    }
    const float bi = b_in[F], bt1 = tau_b1[F];
#pragma unroll
    for (int m = 0; m < 4; m++){
      ushortx4 pf, pt;
#pragma unroll
      for (int i2 = 0; i2 < 4; i2++){ pf[i2] = f2bf(accf[m][i2] + bi); pt[i2] = f2bf(acct[m][i2] + bt1); }
      const size_t base = ((size_t)t * H_DIM + F) * BATCH + m * 16 + q * 4;
      *(ushortx4*)(A_in + base) = pf;
      *(ushortx4*)(A_tau + base) = pt;
    }
  }
}

// ---------------------------------------------------------------------------
// Kernel S: persistent scan. 64 WGs x 256 thr (1/CU), agent-scope comm only
// (round-0 known-good mechanism: __hip_atomic relaxed AGENT, no sc-bit asm).
// Structure kept from round 3: 8 clusters x 8 rows, 8 ranks x 64 feats,
// full-K weight frags per wave -> no cross-wave LDS reduction, one barrier
// fewer, 36B readback/thread, A prefetch issued before the poll.
// ---------------------------------------------------------------------------
__global__ __launch_bounds__(256, 1) void scan_kernel(
  const float* __restrict__ h0, const float* __restrict__ W_rec,
  const float* __restrict__ tau_w1, const float* __restrict__ tau_w2,
  const float* __restrict__ tau_b2_p, const float* __restrict__ gamma,
  const float* __restrict__ beta,
  const unsigned short* __restrict__ A_in, const unsigned short* __restrict__ A_tau,
  unsigned short* __restrict__ bc_f, float* __restrict__ bc_td,
  unsigned int* __restrict__ flags,
  float* __restrict__ out0, float* __restrict__ outh, float* __restrict__ outtau)
{
  __shared__ unsigned short hB[16 * HSTR];   // rows 8..15 stay zero (MFMA M=16 pad)

  const int tid = threadIdx.x;
  const int cl   = blockIdx.x & (NCL - 1);
  const int rank = blockIdx.x >> 3;

  for (int idx = tid; idx < 16 * HSTR; idx += 256) hB[idx] = 0;

  const int w = tid >> 6, l64 = tid & 63, l15 = tid & 15, q = (tid & 63) >> 4;
  const int fl = l15;
  const int rb0 = (l64 >> 4) * 4;            // producer row base; valid if < 8
  const bool pvalid = (l64 < 32);
  const int F0 = rank * FPW + w * 16;        // this wave's 16 output feats
  const int Fl = F0 + l15;
  const int rr = tid >> 5;                   // consumer row 0..7
  const int cc = tid & 31;                   // consumer 16-feat chunk

  // ---- weights -> registers: full K=512 for 16 feats per wave ----
  short8 wr[16], wt[16];
#pragma unroll
  for (int kc = 0; kc < 16; kc++){
    const int k = kc * 32 + q * 8;
    wr[kc] = cvt8(&W_rec[(size_t)Fl * H_DIM + k]);
    wt[kc] = cvt8(&tau_w1[(size_t)Fl * (I_DIM + H_DIM) + I_DIM + k]);
  }
  const float tw2v = tau_w2[Fl];
  const float tb2 = tau_b2_p[0];
  __syncthreads();   // hB zero-init done before h0 fill

  // ---- consumer state: h, gamma, beta in registers ----
  float h_reg[16], gamr[16], betr[16];
  {
    const int b = cl * ROWS + rr;
#pragma unroll
    for (int j = 0; j < 16; j++){
      float hv = h0[(size_t)b * H_DIM + cc * 16 + j];
      h_reg[j] = hv;
      hB[rr * HSTR + cc * 16 + j] = f2bf(hv);
      gamr[j] = gamma[cc * 16 + j];
      betr[j] = beta[cc * 16 + j];
    }
  }

  // prefetch A terms for t=0 (producer layout: 4 consecutive rows per lane)
  ushortx4 afr = (ushortx4){0,0,0,0}, atr = (ushortx4){0,0,0,0};
  if (pvalid){
    const size_t aidx = ((size_t)Fl) * BATCH + cl * ROWS + rb0;
    afr = *(const ushortx4*)&A_in[aidx];
    atr = *(const ushortx4*)&A_tau[aidx];
  }
  __syncthreads();

  for (int t = 0; t < S_LEN; t++){
    const int par = t & 1;

    // ---- producer: full-K matvec, 16 feats x 8 rows (rows 8..15 zero pad)
    floatx4 af = {0,0,0,0}, at4 = {0,0,0,0};
#pragma unroll
    for (int kc = 0; kc < 16; kc++){
      short8 ha = *(const short8*)&hB[l15 * HSTR + kc * 32 + q * 8];
      af  = __builtin_amdgcn_mfma_f32_16x16x32_bf16(ha, wr[kc], af,  0, 0, 0);
      at4 = __builtin_amdgcn_mfma_f32_16x16x32_bf16(ha, wt[kc], at4, 0, 0, 0);
    }

    // epilogue: tanh, broadcast f (packed bf16 pairs), tau partial dot
    unsigned short* bcF = bc_f + ((size_t)(par * NCL + cl) * ROWS) * H_DIM;
    float pd[4];
#pragma unroll
    for (int i2 = 0; i2 < 4; i2++){
      float vf = fast_tanh(af[i2]  + bf2f(afr[i2]));
      float vt = fast_tanh(at4[i2] + bf2f(atr[i2]));
      pd[i2] = vt * tw2v;
      unsigned pv = (unsigned)f2bf(vf);
      unsigned ov = (unsigned)__shfl_xor((int)pv, 1);
      if (pvalid && !(fl & 1)){
        unsigned short* p = bcF + (size_t)(rb0 + i2) * H_DIM + F0 + fl;
        __hip_atomic_store((unsigned*)p, pv | (ov << 16),
                           __ATOMIC_RELAXED, __HIP_MEMORY_SCOPE_AGENT);
      }
    }
#pragma unroll
    for (int i2 = 0; i2 < 4; i2++){
      pd[i2] += __shfl_xor(pd[i2], 1);
      pd[i2] += __shfl_xor(pd[i2], 2);
      pd[i2] += __shfl_xor(pd[i2], 4);
      pd[i2] += __shfl_xor(pd[i2], 8);
    }
    if (pvalid && fl == 0){
      float* p = bc_td + ((size_t)(par * NCL + cl) * 32 + rank * 4 + w) * ROWS + rb0;
#pragma unroll
      for (int i2 = 0; i2 < 4; i2++)
        __hip_atomic_store(p + i2, pd[i2], __ATOMIC_RELAXED, __HIP_MEMORY_SCOPE_AGENT);
    }

    // drain own stores, then store-only arrival flag
    __builtin_amdgcn_s_waitcnt(0);
    __syncthreads();
    if (tid == 0)
      __hip_atomic_store(&flags[cl * NRK + rank], (unsigned)(t + 1),
                         __ATOMIC_RELAXED, __HIP_MEMORY_SCOPE_AGENT);
    // prefetch A for t+1 — in flight during the poll wait
    if (t + 1 < S_LEN && pvalid){
      const size_t aidx = ((size_t)(t + 1) * H_DIM + Fl) * BATCH + cl * ROWS + rb0;
      afr = *(const ushortx4*)&A_in[aidx];
      atr = *(const ushortx4*)&A_tau[aidx];
    }
    if (w == 0 && l64 < NRK){
      const unsigned tgt = (unsigned)(t + 1);
      const unsigned int* fp = &flags[cl * NRK + l64];
      int guard = 0;
      while (__hip_atomic_load(fp, __ATOMIC_RELAXED, __HIP_MEMORY_SCOPE_AGENT) < tgt){
        if (++guard > POLL_CAP) break;   // bounded: fail visibly, never hang
        __builtin_amdgcn_s_sleep(1);
      }
    }
    asm volatile("" ::: "memory");
    __syncthreads();

    // ---- consumer: readback full f slice + tau partial (agent relaxed) ----
    const unsigned long long* p64 = (const unsigned long long*)
      (bc_f + (((size_t)(par * NCL + cl) * ROWS) + rr) * H_DIM + cc * 16);
    const float* tdp = bc_td + ((size_t)(par * NCL + cl) * 32 + cc) * ROWS + rr;
    unsigned long long v0 = __hip_atomic_load(p64 + 0, __ATOMIC_RELAXED, __HIP_MEMORY_SCOPE_AGENT);
    unsigned long long v1 = __hip_atomic_load(p64 + 1, __ATOMIC_RELAXED, __HIP_MEMORY_SCOPE_AGENT);
    unsigned long long v2 = __hip_atomic_load(p64 + 2, __ATOMIC_RELAXED, __HIP_MEMORY_SCOPE_AGENT);
    unsigned long long v3 = __hip_atomic_load(p64 + 3, __ATOMIC_RELAXED, __HIP_MEMORY_SCOPE_AGENT);
    float td = __hip_atomic_load(tdp, __ATOMIC_RELAXED, __HIP_MEMORY_SCOPE_AGENT);

    td += __shfl_xor(td, 1); td += __shfl_xor(td, 2);
    td += __shfl_xor(td, 4); td += __shfl_xor(td, 8);
    td += __shfl_xor(td, 16);
    const float tau = 1.0f + 9.0f * fast_sigmoid(td + tb2);
    const float c2 = 0.1f / tau, c1 = 1.0f - c2;

    float fv[16];
#pragma unroll
    for (int e = 0; e < 4; e++){
      fv[e]      = bf2f((unsigned short)(v0 >> (16 * e)));
      fv[4 + e]  = bf2f((unsigned short)(v1 >> (16 * e)));
      fv[8 + e]  = bf2f((unsigned short)(v2 >> (16 * e)));
      fv[12 + e] = bf2f((unsigned short)(v3 >> (16 * e)));
    }
    float hp[16]; float s1 = 0.f, s2 = 0.f;
#pragma unroll
    for (int j = 0; j < 16; j++){
      float v = c1 * h_reg[j] + c2 * fv[j];
      hp[j] = v; s1 += v; s2 += v * v;
    }
    s1 += __shfl_xor(s1, 1);  s2 += __shfl_xor(s2, 1);
    s1 += __shfl_xor(s1, 2);  s2 += __shfl_xor(s2, 2);
    s1 += __shfl_xor(s1, 4);  s2 += __shfl_xor(s2, 4);
    s1 += __shfl_xor(s1, 8);  s2 += __shfl_xor(s2, 8);
    s1 += __shfl_xor(s1, 16); s2 += __shfl_xor(s2, 16);
    const float mu = s1 * (1.0f / 512.0f);
    const float var = s2 * (1.0f / 512.0f) - mu * mu;
    const float rs = rsqrtf(var + 1e-5f);
#pragma unroll
    for (int j = 0; j < 16; j++) h_reg[j] = (hp[j] - mu) * rs * gamr[j] + betr[j];

    // h -> LDS bf16 for next matvec
#pragma unroll
    for (int u = 0; u < 2; u++){
      short8 hv;
#pragma unroll
      for (int e = 0; e < 8; e++) hv[e] = (short)f2bf(h_reg[u * 8 + e]);
      *(short8*)&hB[rr * HSTR + cc * 16 + u * 8] = hv;
    }

    // outputs: rank r owns batch row rr == r (each row written exactly once)
    if (rr == rank){
      float* dst = out0 + ((size_t)(cl * ROWS + rr) * S_LEN + t) * H_DIM + cc * 16;
#pragma unroll
      for (int j = 0; j < 16; j++) dst[j] = h_reg[j];
      if (cc == 0) outtau[(size_t)(cl * ROWS + rr) * S_LEN + t] = tau;
      if (t == S_LEN - 1){
        float* dh = outh + (size_t)(cl * ROWS + rr) * H_DIM + cc * 16;
#pragma unroll
        for (int j = 0; j < 16; j++) dh[j] = h_reg[j];
      }
    }
    __syncthreads();
  }
}

extern "C" void kernel_launch(void* const* d_in, const int* in_sizes, int n_in,
                              void* d_out, int out_size, void* d_ws, size_t ws_size,
                              hipStream_t stream) {
  const float* x      = (const float*)d_in[0];
  const float* h0     = (const float*)d_in[1];
  const float* W_in   = (const float*)d_in[2];
  const float* b_in   = (const float*)d_in[3];
  const float* W_rec  = (const float*)d_in[4];
  const float* tau_w1 = (const float*)d_in[5];
  const float* tau_b1 = (const float*)d_in[6];
  const float* tau_w2 = (const float*)d_in[7];
  const float* tau_b2 = (const float*)d_in[8];
  const float* gamma  = (const float*)d_in[9];
  const float* beta   = (const float*)d_in[10];

  char* ws = (char*)d_ws;
  unsigned short* A_in   = (unsigned short*)(ws);                 // 67,108,864 B
  unsigned short* A_tau  = (unsigned short*)(ws + 67108864);      // 67,108,864 B
  unsigned short* bc_f   = (unsigned short*)(ws + 134217728);     // 131,072 B
  float*          bc_td  = (float*)(ws + 134348800);              // 16,384 B
  unsigned int*   flags  = (unsigned int*)(ws + 134365184);       // 1,024 B
  unsigned short* Wbf    = (unsigned short*)(ws + 134366208);     // 262,144 B
  unsigned short* Tbf    = (unsigned short*)(ws + 134628352);     // 262,144 B

  float* out0   = (float*)d_out;
  float* outh   = out0 + (size_t)BATCH * S_LEN * H_DIM;           // 33,554,432
  float* outtau = outh + (size_t)BATCH * H_DIM;                   // +32,768

  hipMemsetAsync(flags, 0, 1024, stream);
  convert_weights_kernel<<<dim3(H_DIM), 256, 0, stream>>>(W_in, tau_w1, Wbf, Tbf);
  precompute_kernel<<<dim3(S_LEN), 256, 0, stream>>>(x, Wbf, Tbf, b_in, tau_b1, A_in, A_tau);
  scan_kernel<<<dim3(NCL * NRK), 256, 0, stream>>>(h0, W_rec, tau_w1, tau_w2, tau_b2, gamma, beta,
                                                   A_in, A_tau, bc_f, bc_td, flags,
                                                   out0, outh, outtau);
}